// Round 20
// baseline (100.546 us; speedup 1.0000x reference)
//
#include <hip/hip_runtime.h>
#include <hip/hip_bf16.h>
#include <hip/hip_fp16.h>

// Forbid FMA contraction for plain fp expressions in ALL device code below:
// the kNN ranking must bit-match the reference's uncontracted fp32 expression
//   pd[i,j] = 2*inner(i,j) - xx[i] - xx[j]
// (rounds 4/6/8/10/11/13/14/16/17/18/19 passed uncontracted; round 5
// regressed when the compiler fused 2*inner-xxi into v_fma_f32). Explicit
// fmaf() calls are NOT affected -- the approx prefilter exploits that.
#pragma clang fp contract(off)

// B=4, N=4096, C=128, K=32. All fp32. top-K LARGEST pd, tie -> lowest index.
// Round 20: kill pass-2's coordinate re-reads. r19's knn reads the 48KB xyz
// planes TWICE per query = 1.6GB through L1/L2 (~46us at L2 BW) -- the
// dominant term (VALU ~16us). Now pass 1 caches approx-pd as packed __half2
// in 32 REGISTERS (static indexing); pass 2 is a register scan, zero loads.
// Guarantee chain: exact-top-32 => pd_approx >= m32 - 2delta (r18/r19);
// f16 RTN storage err <= 0.008 (|pd|<=32); compare f16(pd) >= m32 - 2^-5
// (covers both with 2x headroom). Survivors get the bit-exact uncontracted
// re-key as before => final ranking bits unchanged. Expected extras ~+2.
// Selection/pool/linear machinery r19-verbatim.

constexpr int NB   = 4;
constexpr int NP   = 4096;
constexpr int NC   = 128;
constexpr int NK   = 32;
constexpr int NT   = 256;   // linear kernel block size

// approx pd for one candidate (fmaf allowed; bounded vs exact by ~1e-4)
__device__ __forceinline__ float pd_approx1(
    float x, float y, float z, float qx, float qy, float qz, float xxi)
{
    const float xxj   = fmaf(x, x, fmaf(y, y, z * z));
    const float inner = fmaf(qx, x, fmaf(qy, y, qz * z));
    return fmaf(2.0f, inner, -xxi) - xxj;
}

// ---------------------------------------------------------------------------
// Kernel A: one wave per query. kNN (reg-cached prefilter + exact refine) +
// mean pool. Blocks 0..255 also transpose one 64-elem slice of W -> Wt.
// ---------------------------------------------------------------------------
__global__ __launch_bounds__(64, 4) void knn_wave_kernel(
    const float* __restrict__ xyz,    // [B,3,N]
    const float* __restrict__ feats,  // [B,N,C]
    const float* __restrict__ W,      // [C,C]
    float* __restrict__ Wt,           // [C,C] transposed out (or nullptr)
    float* __restrict__ pooled)       // [B*N, C] (d_out, fp32 temp)
{
    const int bi = blockIdx.x;
    const int b  = bi >> 12;
    const int i  = bi & (NP - 1);
    const int l  = threadIdx.x;       // lane 0..63

    // spread W-transpose over the first 256 blocks (1 coalesced read each)
    if (Wt != nullptr && bi < 256) {
        const int e = bi * 64 + l;
        Wt[(e & (NC - 1)) * NC + (e >> 7)] = W[e];
    }

    const float* xb = xyz + (size_t)b * 3 * NP;
    const float qx  = xb[i];
    const float qy  = xb[NP + i];
    const float qz  = xb[2 * NP + i];
    const float xxi = (qx * qx + qy * qy) + qz * qz;  // uncontracted (exact)

    // -- pass 1: approx pd over 64 candidates; cache as packed f16 in regs --
    __half2 ph[32];                   // fully-static indexing -> stays in VGPR
    float tmax = -3.0e38f;
    #pragma unroll
    for (int q = 0; q < 16; ++q) {
        const int j4 = q * 256 + l * 4;
        const float4 X = *(const float4*)&xb[j4];
        const float4 Y = *(const float4*)&xb[NP + j4];
        const float4 Z = *(const float4*)&xb[2 * NP + j4];
        const float p0 = pd_approx1(X.x, Y.x, Z.x, qx, qy, qz, xxi);
        const float p1 = pd_approx1(X.y, Y.y, Z.y, qx, qy, qz, xxi);
        const float p2 = pd_approx1(X.z, Y.z, Z.z, qx, qy, qz, xxi);
        const float p3 = pd_approx1(X.w, Y.w, Z.w, qx, qy, qz, xxi);
        tmax = fmaxf(tmax, fmaxf(fmaxf(p0, p1), fmaxf(p2, p3)));
        ph[2 * q]     = __floats2half2_rn(p0, p1);
        ph[2 * q + 1] = __floats2half2_rn(p2, p3);
    }

    // -- bitonic sort (desc) of the 64 lane-maxima; lane r = r-th largest --
    {
        float v = tmax;
        #pragma unroll
        for (int k = 2; k <= 64; k <<= 1) {
            #pragma unroll
            for (int jj = k >> 1; jj >= 1; jj >>= 1) {
                const float o = __shfl_xor(v, jj, 64);
                const bool wantMax = (((l & k) == 0) == ((l & jj) == 0));
                v = (wantMax == (o > v)) ? o : v;
            }
        }
        tmax = v;   // reuse register: sorted value
    }
    const float m32 = __shfl(tmax, 31, 64);   // 32nd largest lane-max
    // margin 2^-5: covers 2*delta (approx-vs-exact, <=2e-4) + f16 RTN
    // storage error (<=0.008 for |pd|<=32) with >2x headroom.
    const float thr = m32 - 0x1p-5f;

    __shared__ int      s_sj[128];
    __shared__ unsigned s_sk[128];
    __shared__ int      s_sel[NK];
    __shared__ unsigned s_scnt;

    if (l == 0) s_scnt = 0;
    if (l < NK) s_sel[l] = 0;                 // defensive
    __syncthreads();                          // 1-wave: trivial

    // -- pass 2: register scan of cached f16 pd; zero loads --
    #pragma unroll
    for (int q = 0; q < 16; ++q) {
        const int j4 = q * 256 + l * 4;
        const float f0 = __low2float(ph[2 * q]);
        const float f1 = __high2float(ph[2 * q]);
        const float f2 = __low2float(ph[2 * q + 1]);
        const float f3 = __high2float(ph[2 * q + 1]);
        if (f0 >= thr) { const unsigned p = atomicAdd(&s_scnt, 1u); if (p < 128u) s_sj[p] = j4 + 0; }
        if (f1 >= thr) { const unsigned p = atomicAdd(&s_scnt, 1u); if (p < 128u) s_sj[p] = j4 + 1; }
        if (f2 >= thr) { const unsigned p = atomicAdd(&s_scnt, 1u); if (p < 128u) s_sj[p] = j4 + 2; }
        if (f3 >= thr) { const unsigned p = atomicAdd(&s_scnt, 1u); if (p < 128u) s_sj[p] = j4 + 3; }
    }
    __syncthreads();

    const int sc = (int)min(s_scnt, 128u);    // >= 32 always (subset property)

    // -- exact re-key: uncontracted reference bits, survivors only --
    for (int s = l; s < sc; s += 64) {
        const int j = s_sj[s];
        const float px = xb[j];
        const float py = xb[NP + j];
        const float pz = xb[2 * NP + j];
        const float xxj   = (px * px + py * py) + pz * pz;   // no FMA (pragma)
        const float inner = (qx * px + qy * py) + qz * pz;   // no FMA (pragma)
        const float pd    = (2.0f * inner - xxi) - xxj;      // no FMA (pragma)
        const unsigned u  = __float_as_uint(pd);
        s_sk[s] = (u & 0x80000000u) ? ~u : (u | 0x80000000u);
    }
    __syncthreads();

    // -- exact top-32 among survivors by (key desc, idx asc) --
    if (sc <= 64) {
        unsigned long long comp = 0ull;       // padding sorts below all real
        if (l < sc)
            comp = ((unsigned long long)s_sk[l] << 32) |
                   (unsigned)(~(unsigned)s_sj[l]);
        #pragma unroll
        for (int k = 2; k <= 64; k <<= 1) {
            #pragma unroll
            for (int jj = k >> 1; jj >= 1; jj >>= 1) {
                const unsigned long long other = __shfl_xor(comp, jj, 64);
                const bool wantMax = (((l & k) == 0) == ((l & jj) == 0));
                comp = (wantMax == (other > comp)) ? other : comp;
            }
        }
        if (l < NK)
            s_sel[l] = (int)(~(unsigned)(comp & 0xffffffffull));
    } else {
        // rare path (65..128 survivors): 2 composites/lane, 32 extractions
        unsigned long long c0 = 0ull, c1 = 0ull;
        if (l < sc)
            c0 = ((unsigned long long)s_sk[l] << 32) |
                 (unsigned)(~(unsigned)s_sj[l]);
        if (l + 64 < sc)
            c1 = ((unsigned long long)s_sk[l + 64] << 32) |
                 (unsigned)(~(unsigned)s_sj[l + 64]);
        for (int r = 0; r < NK; ++r) {
            unsigned long long w = (c0 > c1) ? c0 : c1;
            #pragma unroll
            for (int off = 32; off >= 1; off >>= 1) {
                const unsigned long long o = __shfl_xor(w, off, 64);
                if (o > w) w = o;
            }
            if (c0 == w) c0 = 0ull; else if (c1 == w) c1 = 0ull;
            if (l == 0)
                s_sel[r] = (int)(~(unsigned)(w & 0xffffffffull));
        }
    }
    __syncthreads();

    // -- mean-pool: lane = (4-ch group cg, 16-row half rg); shfl fold --
    const int cg = l & 31;    // channels 4*cg .. 4*cg+3
    const int rg = l >> 5;    // rows rg*16 .. rg*16+15
    const float* fb = feats + (size_t)b * NP * NC;
    float ax = 0.f, ay = 0.f, az = 0.f, aw = 0.f;
    #pragma unroll 4
    for (int k = 0; k < 16; ++k) {
        const int j = s_sel[rg * 16 + k] & (NP - 1);   // fault-proof mask
        const float4 f = *(const float4*)&fb[(size_t)j * NC + cg * 4];
        ax += f.x; ay += f.y; az += f.z; aw += f.w;
    }
    const float bx = __shfl_down(ax, 32, 64);
    const float by = __shfl_down(ay, 32, 64);
    const float bz = __shfl_down(az, 32, 64);
    const float bw = __shfl_down(aw, 32, 64);
    if (l < 32) {
        const float inv = 1.0f / (float)NK;
        float4 s;
        s.x = (ax + bx) * inv;
        s.y = (ay + by) * inv;
        s.z = (az + bz) * inv;
        s.w = (aw + bw) * inv;
        *(float4*)&pooled[(size_t)bi * NC + l * 4] = s;
    }
}

// ---------------------------------------------------------------------------
// Kernel B (v3, r17-verbatim): in-place Linear, 512 blocks x 32 rows.
// ---------------------------------------------------------------------------
constexpr int LROWS = 32;
__global__ __launch_bounds__(NT) void linear_v3_kernel(
    float* __restrict__ io,           // [B*N, C] fp32, in-place
    const float* __restrict__ Wt)     // [C, C] transposed: Wt[c][d]
{
    const int t    = threadIdx.x;
    const int row0 = blockIdx.x * LROWS;

    __shared__ float P[LROWS * NC];   // 16 KiB

    const float4* src4 = (const float4*)(io + (size_t)row0 * NC);
    #pragma unroll
    for (int m = 0; m < 4; ++m)
        ((float4*)P)[m * NT + t] = src4[m * NT + t];
    __syncthreads();

    const int dg = t & 31;            // d = 4*dg .. 4*dg+3
    const int rg = t >> 5;            // rows 4*rg .. 4*rg+3

    float4 a0 = make_float4(0.f,0.f,0.f,0.f);
    float4 a1 = make_float4(0.f,0.f,0.f,0.f);
    float4 a2 = make_float4(0.f,0.f,0.f,0.f);
    float4 a3 = make_float4(0.f,0.f,0.f,0.f);
    const float4* Wt4 = (const float4*)Wt;   // row c = 32 float4
    const float*  Pr  = P + rg * 4 * NC;

#define LSTEP(K, PC)                                                          \
    {                                                                         \
        const float4 w = Wt4[(c4 * 4 + K) * 32 + dg];                         \
        a0.x = fmaf(p0.PC, w.x, a0.x); a0.y = fmaf(p0.PC, w.y, a0.y);         \
        a0.z = fmaf(p0.PC, w.z, a0.z); a0.w = fmaf(p0.PC, w.w, a0.w);         \
        a1.x = fmaf(p1.PC, w.x, a1.x); a1.y = fmaf(p1.PC, w.y, a1.y);         \
        a1.z = fmaf(p1.PC, w.z, a1.z); a1.w = fmaf(p1.PC, w.w, a1.w);         \
        a2.x = fmaf(p2.PC, w.x, a2.x); a2.y = fmaf(p2.PC, w.y, a2.y);         \
        a2.z = fmaf(p2.PC, w.z, a2.z); a2.w = fmaf(p2.PC, w.w, a2.w);         \
        a3.x = fmaf(p3.PC, w.x, a3.x); a3.y = fmaf(p3.PC, w.y, a3.y);         \
        a3.z = fmaf(p3.PC, w.z, a3.z); a3.w = fmaf(p3.PC, w.w, a3.w);         \
    }

    #pragma unroll 4
    for (int c4 = 0; c4 < NC / 4; ++c4) {
        const float4 p0 = *(const float4*)&Pr[c4 * 4];            // b128 reads
        const float4 p1 = *(const float4*)&Pr[NC + c4 * 4];
        const float4 p2 = *(const float4*)&Pr[2 * NC + c4 * 4];
        const float4 p3 = *(const float4*)&Pr[3 * NC + c4 * 4];
        LSTEP(0, x) LSTEP(1, y) LSTEP(2, z) LSTEP(3, w)
    }
#undef LSTEP

    float4* dst4 = (float4*)(io + (size_t)row0 * NC);
    const int r4 = rg * 4;
    dst4[(r4 + 0) * 32 + dg] = a0;    // all staging reads done pre-barrier
    dst4[(r4 + 1) * 32 + dg] = a1;
    dst4[(r4 + 2) * 32 + dg] = a2;
    dst4[(r4 + 3) * 32 + dg] = a3;
}

// ---------------------------------------------------------------------------
// Fallback (ws-less): old 64-row in-place linear reading W directly.
// ---------------------------------------------------------------------------
__global__ __launch_bounds__(NT) void linear_kernel(
    float* __restrict__ io, const float* __restrict__ W)
{
    const int t = threadIdx.x;
    const int row0 = blockIdx.x * 64;
    __shared__ float P[64 * NC];
    const float* src = io + (size_t)row0 * NC;
    #pragma unroll
    for (int m = 0; m < 8; ++m) {
        const int e4 = m * NT + t;
        *(float4*)&P[e4 * 4] = *(const float4*)&src[e4 * 4];
    }
    __syncthreads();
    const int d = t & (NC - 1);
    const int rbase = (t >> 7) * 32;
    float acc[32];
    #pragma unroll
    for (int k = 0; k < 32; ++k) acc[k] = 0.f;
    const float* Wd = W + (size_t)d * NC;
    for (int c4 = 0; c4 < NC / 4; ++c4) {
        const float4 w = *(const float4*)(Wd + c4 * 4);
        #pragma unroll
        for (int k = 0; k < 32; ++k) {
            const float4 pv = *(const float4*)&P[(rbase + k) * NC + c4 * 4];
            acc[k] = fmaf(pv.x, w.x, acc[k]);
            acc[k] = fmaf(pv.y, w.y, acc[k]);
            acc[k] = fmaf(pv.z, w.z, acc[k]);
            acc[k] = fmaf(pv.w, w.w, acc[k]);
        }
    }
    #pragma unroll
    for (int k = 0; k < 32; ++k)
        io[(size_t)(row0 + rbase + k) * NC + d] = acc[k];
}

// ---------------------------------------------------------------------------
extern "C" void kernel_launch(void* const* d_in, const int* in_sizes, int n_in,
                              void* d_out, int out_size, void* d_ws, size_t ws_size,
                              hipStream_t stream) {
    const float* xyz   = nullptr;  // 49152
    const float* feats = nullptr;  // 2097152
    const float* W     = nullptr;  // 16384
    for (int k = 0; k < n_in; ++k) {
        if      (in_sizes[k] == NB * 3 * NP)       xyz   = (const float*)d_in[k];
        else if (in_sizes[k] == NB * NP * NC)      feats = (const float*)d_in[k];
        else if (in_sizes[k] == NC * NC)           W     = (const float*)d_in[k];
    }
    float* out = (float*)d_out;

    const size_t need = sizeof(float) * (size_t)(NC * NC);
    if (ws_size >= need) {
        float* Wt = (float*)d_ws;                  // 64 KiB
        knn_wave_kernel<<<NB * NP, 64, 0, stream>>>(xyz, feats, W, Wt, out);
        linear_v3_kernel<<<NB * NP / LROWS, NT, 0, stream>>>(out, Wt);
    } else {
        knn_wave_kernel<<<NB * NP, 64, 0, stream>>>(xyz, feats, W, nullptr, out);
        linear_kernel<<<NB * NP / 64, NT, 0, stream>>>(out, W);
    }
}

// Round 21
// 84.620 us; speedup vs baseline: 1.1882x; 1.1882x over previous
//
#include <hip/hip_runtime.h>
#include <hip/hip_bf16.h>

// Forbid FMA contraction for plain fp expressions in ALL device code below:
// the kNN ranking must bit-match the reference's uncontracted fp32 expression
//   pd[i,j] = 2*inner(i,j) - xx[i] - xx[j]
// (rounds 4/6/8/10/11/13/14/16/17/18/19 passed uncontracted; round 5
// regressed when the compiler fused 2*inner-xxi into v_fma_f32). Explicit
// fmaf() calls are NOT affected -- the approx prefilter exploits that.
#pragma clang fp contract(off)

// B=4, N=4096, C=128, K=32. All fp32. top-K LARGEST pd, tie -> lowest index.
// Round 21: 4 QUERIES PER WAVE. r19's knn moves 112KB/query through L1
// (pass1 48 + pass2 48 + gather 16) ~ 47us L1-service floor -> 76.5us
// plateau. r20's register-cache fix cost occupancy (71->33%) and lost.
// Now each lane loads its 64 candidates ONCE per pass and computes pd
// against 4 register-resident queries: L1/query = 40KB (2.8x cut), xxj
// shared across queries (-25% main-loop VALU/query). Per-query selection
// (lane-max bitonic m32 - 2^-11 threshold, exact uncontracted re-key,
// composite bitonic top-32, pool) is r19-verbatim, x4 via macros; cold
// rare-path deduped __noinline__. Grid 4096 blocks = 16/CU.
// Spill tripwire: WRITE_SIZE (r18 lesson).

constexpr int NB   = 4;
constexpr int NP   = 4096;
constexpr int NC   = 128;
constexpr int NK   = 32;
constexpr int NT   = 256;   // linear kernel block size
constexpr int NQ   = 4;     // queries per wave

struct QS { float x, y, z, xx; };

__device__ __forceinline__ QS load_q(const float* xb, int i) {
    QS q;
    q.x = xb[i]; q.y = xb[NP + i]; q.z = xb[2 * NP + i];
    q.xx = (q.x * q.x + q.y * q.y) + q.z * q.z;   // uncontracted (exact)
    return q;
}

// approx pd (fmaf allowed; bounded vs exact by delta <= 1e-4)
__device__ __forceinline__ float pdq(float x, float y, float z, float xxj,
                                     const QS& q)
{
    const float inner = fmaf(q.x, x, fmaf(q.y, y, q.z * z));
    return fmaf(2.0f, inner, -q.xx) - xxj;
}

// 64-lane bitonic sort (desc) of per-lane maxima; returns 32nd largest
__device__ __forceinline__ float m32_of(float v, int l) {
    #pragma unroll
    for (int k = 2; k <= 64; k <<= 1) {
        #pragma unroll
        for (int jj = k >> 1; jj >= 1; jj >>= 1) {
            const float o = __shfl_xor(v, jj, 64);
            const bool wantMax = (((l & k) == 0) == ((l & jj) == 0));
            v = (wantMax == (o > v)) ? o : v;
        }
    }
    return __shfl(v, 31, 64);
}

// cold path: 65..128 survivors -> 32 rounds of wave-argmax extraction
__device__ __noinline__ void top32_rare(const int* sj, const unsigned* sk,
                                        int sc, int l, int* sel)
{
    unsigned long long c0 = 0ull, c1 = 0ull;
    if (l < sc)
        c0 = ((unsigned long long)sk[l] << 32) | (unsigned)(~(unsigned)sj[l]);
    if (l + 64 < sc)
        c1 = ((unsigned long long)sk[l + 64] << 32) |
             (unsigned)(~(unsigned)sj[l + 64]);
    for (int r = 0; r < NK; ++r) {
        unsigned long long w = (c0 > c1) ? c0 : c1;
        #pragma unroll
        for (int off = 32; off >= 1; off >>= 1) {
            const unsigned long long o = __shfl_xor(w, off, 64);
            if (o > w) w = o;
        }
        if (c0 == w) c0 = 0ull; else if (c1 == w) c1 = 0ull;
        if (l == 0) sel[r] = (int)(~(unsigned)(w & 0xffffffffull));
    }
}

// exact top-32 among survivors by (key desc, idx asc); writes sel[0..31]
__device__ __forceinline__ void top32_sel(const int* sj, const unsigned* sk,
                                          int sc, int l, int* sel)
{
    if (sc <= 64) {
        unsigned long long comp = 0ull;       // padding sorts below all real
        if (l < sc)
            comp = ((unsigned long long)sk[l] << 32) |
                   (unsigned)(~(unsigned)sj[l]);
        #pragma unroll
        for (int k = 2; k <= 64; k <<= 1) {
            #pragma unroll
            for (int jj = k >> 1; jj >= 1; jj >>= 1) {
                const unsigned long long other = __shfl_xor(comp, jj, 64);
                const bool wantMax = (((l & k) == 0) == ((l & jj) == 0));
                comp = (wantMax == (other > comp)) ? other : comp;
            }
        }
        if (l < NK) sel[l] = (int)(~(unsigned)(comp & 0xffffffffull));
    } else {
        top32_rare(sj, sk, sc, l, sel);
    }
}

// exact re-key: uncontracted reference bits for survivors
__device__ __forceinline__ void rekey(const float* xb, const int* sj,
                                      unsigned* sk, int sc, int l, const QS& q)
{
    for (int s = l; s < sc; s += 64) {
        const int j = sj[s];
        const float px = xb[j];
        const float py = xb[NP + j];
        const float pz = xb[2 * NP + j];
        const float xxj   = (px * px + py * py) + pz * pz;   // no FMA (pragma)
        const float inner = (q.x * px + q.y * py) + q.z * pz;
        const float pd    = (2.0f * inner - q.xx) - xxj;
        const unsigned u  = __float_as_uint(pd);
        sk[s] = (u & 0x80000000u) ? ~u : (u | 0x80000000u);
    }
}

// mean-pool 32 selected rows -> dst[0..127] (fp32)
__device__ __forceinline__ void pool_row(const float* fb, const int* sel,
                                         int l, float* dst)
{
    const int cg = l & 31;    // channels 4*cg .. 4*cg+3
    const int rg = l >> 5;    // rows rg*16 .. rg*16+15
    float ax = 0.f, ay = 0.f, az = 0.f, aw = 0.f;
    #pragma unroll 4
    for (int k = 0; k < 16; ++k) {
        const int j = sel[rg * 16 + k] & (NP - 1);   // fault-proof mask
        const float4 f = *(const float4*)&fb[(size_t)j * NC + cg * 4];
        ax += f.x; ay += f.y; az += f.z; aw += f.w;
    }
    const float bx = __shfl_down(ax, 32, 64);
    const float by = __shfl_down(ay, 32, 64);
    const float bz = __shfl_down(az, 32, 64);
    const float bw = __shfl_down(aw, 32, 64);
    if (l < 32) {
        const float inv = 1.0f / (float)NK;
        float4 s;
        s.x = (ax + bx) * inv; s.y = (ay + by) * inv;
        s.z = (az + bz) * inv; s.w = (aw + bw) * inv;
        *(float4*)&dst[l * 4] = s;
    }
}

// ---------------------------------------------------------------------------
// Kernel A: one wave, FOUR queries. Blocks 0..255 also transpose W -> Wt.
// ---------------------------------------------------------------------------
__global__ __launch_bounds__(64, 4) void knn_wave4_kernel(
    const float* __restrict__ xyz,    // [B,3,N]
    const float* __restrict__ feats,  // [B,N,C]
    const float* __restrict__ W,      // [C,C]
    float* __restrict__ Wt,           // [C,C] transposed out (or nullptr)
    float* __restrict__ pooled)       // [B*N, C] (d_out, fp32 temp)
{
    const int blk = blockIdx.x;       // 0 .. NB*NP/NQ-1 (4096)
    const int b   = blk >> 10;        // 1024 blocks per batch
    const int i0  = (blk & 1023) * NQ;
    const int l   = threadIdx.x;      // lane 0..63

    // spread W-transpose over the first 256 blocks (1 coalesced read each)
    if (Wt != nullptr && blk < 256) {
        const int e = blk * 64 + l;
        Wt[(e & (NC - 1)) * NC + (e >> 7)] = W[e];
    }

    const float* xb = xyz + (size_t)b * 3 * NP;
    const QS q0 = load_q(xb, i0 + 0);
    const QS q1 = load_q(xb, i0 + 1);
    const QS q2 = load_q(xb, i0 + 2);
    const QS q3 = load_q(xb, i0 + 3);

    // -- pass 1: running maxima of approx pd (xxj shared across queries) --
    float t0 = -3.0e38f, t1 = -3.0e38f, t2 = -3.0e38f, t3 = -3.0e38f;
#define CAND1(CX, CY, CZ) {                                                   \
        const float xxj = fmaf(CX, CX, fmaf(CY, CY, CZ * CZ));                \
        t0 = fmaxf(t0, pdq(CX, CY, CZ, xxj, q0));                             \
        t1 = fmaxf(t1, pdq(CX, CY, CZ, xxj, q1));                             \
        t2 = fmaxf(t2, pdq(CX, CY, CZ, xxj, q2));                             \
        t3 = fmaxf(t3, pdq(CX, CY, CZ, xxj, q3)); }
    #pragma unroll 2
    for (int it = 0; it < 16; ++it) {
        const int j4 = it * 256 + l * 4;
        const float4 X = *(const float4*)&xb[j4];
        const float4 Y = *(const float4*)&xb[NP + j4];
        const float4 Z = *(const float4*)&xb[2 * NP + j4];
        CAND1(X.x, Y.x, Z.x) CAND1(X.y, Y.y, Z.y)
        CAND1(X.z, Y.z, Z.z) CAND1(X.w, Y.w, Z.w)
    }
#undef CAND1

    // per-query threshold: 32nd largest lane-max minus margin (>= 2*delta)
    const float thr0 = m32_of(t0, l) - 0x1p-11f;
    const float thr1 = m32_of(t1, l) - 0x1p-11f;
    const float thr2 = m32_of(t2, l) - 0x1p-11f;
    const float thr3 = m32_of(t3, l) - 0x1p-11f;

    __shared__ int      s_sj[NQ][128];
    __shared__ unsigned s_sk[NQ][128];
    __shared__ int      s_sel[NK];
    __shared__ unsigned s_cnt[NQ];

    if (l < NQ) s_cnt[l] = 0;
    __syncthreads();                          // 1-wave: trivial

    // -- pass 2: recompute (L1-hot) and gather survivors for all 4 queries --
#define CAND2(CX, CY, CZ, JOFF) {                                             \
        const float xxj = fmaf(CX, CX, fmaf(CY, CY, CZ * CZ));                \
        const float pA = pdq(CX, CY, CZ, xxj, q0);                            \
        const float pB = pdq(CX, CY, CZ, xxj, q1);                            \
        const float pC = pdq(CX, CY, CZ, xxj, q2);                            \
        const float pD = pdq(CX, CY, CZ, xxj, q3);                            \
        if (pA >= thr0) { const unsigned p = atomicAdd(&s_cnt[0], 1u);        \
                          if (p < 128u) s_sj[0][p] = j4 + (JOFF); }           \
        if (pB >= thr1) { const unsigned p = atomicAdd(&s_cnt[1], 1u);        \
                          if (p < 128u) s_sj[1][p] = j4 + (JOFF); }           \
        if (pC >= thr2) { const unsigned p = atomicAdd(&s_cnt[2], 1u);        \
                          if (p < 128u) s_sj[2][p] = j4 + (JOFF); }           \
        if (pD >= thr3) { const unsigned p = atomicAdd(&s_cnt[3], 1u);        \
                          if (p < 128u) s_sj[3][p] = j4 + (JOFF); } }
    #pragma unroll 2
    for (int it = 0; it < 16; ++it) {
        const int j4 = it * 256 + l * 4;
        const float4 X = *(const float4*)&xb[j4];
        const float4 Y = *(const float4*)&xb[NP + j4];
        const float4 Z = *(const float4*)&xb[2 * NP + j4];
        CAND2(X.x, Y.x, Z.x, 0) CAND2(X.y, Y.y, Z.y, 1)
        CAND2(X.z, Y.z, Z.z, 2) CAND2(X.w, Y.w, Z.w, 3)
    }
#undef CAND2
    __syncthreads();

    const float* fb = feats + (size_t)b * NP * NC;

    // -- per-query epilogue: re-key -> exact top-32 -> pool -> store --
#define EPI(QI, QREF) {                                                       \
        const int sc = (int)min(s_cnt[QI], 128u);                             \
        rekey(xb, s_sj[QI], s_sk[QI], sc, l, QREF);                           \
        __syncthreads();                                                      \
        top32_sel(s_sj[QI], s_sk[QI], sc, l, s_sel);                          \
        __syncthreads();                                                      \
        pool_row(fb, s_sel, l,                                                \
                 pooled + (size_t)((b << 12) | (i0 + QI)) * NC);              \
        __syncthreads(); }
    EPI(0, q0) EPI(1, q1) EPI(2, q2) EPI(3, q3)
#undef EPI
}

// ---------------------------------------------------------------------------
// Kernel B (v3, r17-verbatim): in-place Linear, 512 blocks x 32 rows.
// ---------------------------------------------------------------------------
constexpr int LROWS = 32;
__global__ __launch_bounds__(NT) void linear_v3_kernel(
    float* __restrict__ io,           // [B*N, C] fp32, in-place
    const float* __restrict__ Wt)     // [C, C] transposed: Wt[c][d]
{
    const int t    = threadIdx.x;
    const int row0 = blockIdx.x * LROWS;

    __shared__ float P[LROWS * NC];   // 16 KiB

    const float4* src4 = (const float4*)(io + (size_t)row0 * NC);
    #pragma unroll
    for (int m = 0; m < 4; ++m)
        ((float4*)P)[m * NT + t] = src4[m * NT + t];
    __syncthreads();

    const int dg = t & 31;            // d = 4*dg .. 4*dg+3
    const int rg = t >> 5;            // rows 4*rg .. 4*rg+3

    float4 a0 = make_float4(0.f,0.f,0.f,0.f);
    float4 a1 = make_float4(0.f,0.f,0.f,0.f);
    float4 a2 = make_float4(0.f,0.f,0.f,0.f);
    float4 a3 = make_float4(0.f,0.f,0.f,0.f);
    const float4* Wt4 = (const float4*)Wt;   // row c = 32 float4
    const float*  Pr  = P + rg * 4 * NC;

#define LSTEP(K, PC)                                                          \
    {                                                                         \
        const float4 w = Wt4[(c4 * 4 + K) * 32 + dg];                         \
        a0.x = fmaf(p0.PC, w.x, a0.x); a0.y = fmaf(p0.PC, w.y, a0.y);         \
        a0.z = fmaf(p0.PC, w.z, a0.z); a0.w = fmaf(p0.PC, w.w, a0.w);         \
        a1.x = fmaf(p1.PC, w.x, a1.x); a1.y = fmaf(p1.PC, w.y, a1.y);         \
        a1.z = fmaf(p1.PC, w.z, a1.z); a1.w = fmaf(p1.PC, w.w, a1.w);         \
        a2.x = fmaf(p2.PC, w.x, a2.x); a2.y = fmaf(p2.PC, w.y, a2.y);         \
        a2.z = fmaf(p2.PC, w.z, a2.z); a2.w = fmaf(p2.PC, w.w, a2.w);         \
        a3.x = fmaf(p3.PC, w.x, a3.x); a3.y = fmaf(p3.PC, w.y, a3.y);         \
        a3.z = fmaf(p3.PC, w.z, a3.z); a3.w = fmaf(p3.PC, w.w, a3.w);         \
    }

    #pragma unroll 4
    for (int c4 = 0; c4 < NC / 4; ++c4) {
        const float4 p0 = *(const float4*)&Pr[c4 * 4];            // b128 reads
        const float4 p1 = *(const float4*)&Pr[NC + c4 * 4];
        const float4 p2 = *(const float4*)&Pr[2 * NC + c4 * 4];
        const float4 p3 = *(const float4*)&Pr[3 * NC + c4 * 4];
        LSTEP(0, x) LSTEP(1, y) LSTEP(2, z) LSTEP(3, w)
    }
#undef LSTEP

    float4* dst4 = (float4*)(io + (size_t)row0 * NC);
    const int r4 = rg * 4;
    dst4[(r4 + 0) * 32 + dg] = a0;    // all staging reads done pre-barrier
    dst4[(r4 + 1) * 32 + dg] = a1;
    dst4[(r4 + 2) * 32 + dg] = a2;
    dst4[(r4 + 3) * 32 + dg] = a3;
}

// ---------------------------------------------------------------------------
// Fallback (ws-less): old 64-row in-place linear reading W directly.
// ---------------------------------------------------------------------------
__global__ __launch_bounds__(NT) void linear_kernel(
    float* __restrict__ io, const float* __restrict__ W)
{
    const int t = threadIdx.x;
    const int row0 = blockIdx.x * 64;
    __shared__ float P[64 * NC];
    const float* src = io + (size_t)row0 * NC;
    #pragma unroll
    for (int m = 0; m < 8; ++m) {
        const int e4 = m * NT + t;
        *(float4*)&P[e4 * 4] = *(const float4*)&src[e4 * 4];
    }
    __syncthreads();
    const int d = t & (NC - 1);
    const int rbase = (t >> 7) * 32;
    float acc[32];
    #pragma unroll
    for (int k = 0; k < 32; ++k) acc[k] = 0.f;
    const float* Wd = W + (size_t)d * NC;
    for (int c4 = 0; c4 < NC / 4; ++c4) {
        const float4 w = *(const float4*)(Wd + c4 * 4);
        #pragma unroll
        for (int k = 0; k < 32; ++k) {
            const float4 pv = *(const float4*)&P[(rbase + k) * NC + c4 * 4];
            acc[k] = fmaf(pv.x, w.x, acc[k]);
            acc[k] = fmaf(pv.y, w.y, acc[k]);
            acc[k] = fmaf(pv.z, w.z, acc[k]);
            acc[k] = fmaf(pv.w, w.w, acc[k]);
        }
    }
    #pragma unroll
    for (int k = 0; k < 32; ++k)
        io[(size_t)(row0 + rbase + k) * NC + d] = acc[k];
}

// ---------------------------------------------------------------------------
extern "C" void kernel_launch(void* const* d_in, const int* in_sizes, int n_in,
                              void* d_out, int out_size, void* d_ws, size_t ws_size,
                              hipStream_t stream) {
    const float* xyz   = nullptr;  // 49152
    const float* feats = nullptr;  // 2097152
    const float* W     = nullptr;  // 16384
    for (int k = 0; k < n_in; ++k) {
        if      (in_sizes[k] == NB * 3 * NP)       xyz   = (const float*)d_in[k];
        else if (in_sizes[k] == NB * NP * NC)      feats = (const float*)d_in[k];
        else if (in_sizes[k] == NC * NC)           W     = (const float*)d_in[k];
    }
    float* out = (float*)d_out;

    const size_t need = sizeof(float) * (size_t)(NC * NC);
    if (ws_size >= need) {
        float* Wt = (float*)d_ws;                  // 64 KiB
        knn_wave4_kernel<<<NB * NP / NQ, 64, 0, stream>>>(xyz, feats, W, Wt, out);
        linear_v3_kernel<<<NB * NP / LROWS, NT, 0, stream>>>(out, Wt);
    } else {
        knn_wave4_kernel<<<NB * NP / NQ, 64, 0, stream>>>(xyz, feats, W, nullptr, out);
        linear_kernel<<<NB * NP / 64, NT, 0, stream>>>(out, W);
    }
}

// Round 22
// 75.143 us; speedup vs baseline: 1.3381x; 1.1261x over previous
//
#include <hip/hip_runtime.h>
#include <hip/hip_bf16.h>

// Forbid FMA contraction for plain fp expressions in ALL device code below:
// the kNN ranking must bit-match the reference's uncontracted fp32 expression
//   pd[i,j] = 2*inner(i,j) - xx[i] - xx[j]
// (rounds 4/6/8/10/11/13/14/16/17/18/19/21 passed uncontracted; round 5
// regressed when the compiler fused 2*inner-xxi into v_fma_f32). Explicit
// fmaf() calls are NOT affected -- the approx prefilter exploits that.
#pragma clang fp contract(off)

// B=4, N=4096, C=128, K=32. All fp32. top-K LARGEST pd, tie -> lowest index.
// Round 22: 2-WAVE COOPERATIVE BLOCKS (128 thr) per 4 queries. r21 had only
// 4096 waves = 16/CU (occupancy 35%, VALUBusy 57%) -- latency overlap was
// the new limit. Now each wave scans HALF the candidates (32/lane): wave
// count doubles to 32/CU, per-wave VALU halves, per-query L1 traffic stays
// 40KB. Threshold: per-wave bitonic sort of 64 lane-maxima -> top-32 of
// each wave to LDS -> full sort of merged 64 -> m32(128 lane-maxima) =
// sorted[31] (32 largest of 128 maxima are 32 distinct candidates =>
// m32 <= v32; top-32 of union lies in union of per-wave top-32s).
// thr = m32 - 2^-11 (same >=2*delta chain). Epilogue parallelized: wave 0
// refines+pools q0,q1; wave 1 q2,q3 (wave-local, no barriers inside).
// 3 real block barriers. Exact re-key + composite bitonic unchanged.
// Spill tripwire: WRITE_SIZE (r18 lesson).

constexpr int NB   = 4;
constexpr int NP   = 4096;
constexpr int NC   = 128;
constexpr int NK   = 32;
constexpr int NT   = 256;   // linear kernel block size
constexpr int NQ   = 4;     // queries per block

struct QS { float x, y, z, xx; };

__device__ __forceinline__ QS load_q(const float* xb, int i) {
    QS q;
    q.x = xb[i]; q.y = xb[NP + i]; q.z = xb[2 * NP + i];
    q.xx = (q.x * q.x + q.y * q.y) + q.z * q.z;   // uncontracted (exact)
    return q;
}

// approx pd (fmaf allowed; bounded vs exact by delta <= 1e-4)
__device__ __forceinline__ float pdq(float x, float y, float z, float xxj,
                                     const QS& q)
{
    const float inner = fmaf(q.x, x, fmaf(q.y, y, q.z * z));
    return fmaf(2.0f, inner, -q.xx) - xxj;
}

// 64-lane bitonic sort (desc); returns this lane's sorted value
__device__ __forceinline__ float sort64_desc(float v, int l) {
    #pragma unroll
    for (int k = 2; k <= 64; k <<= 1) {
        #pragma unroll
        for (int jj = k >> 1; jj >= 1; jj >>= 1) {
            const float o = __shfl_xor(v, jj, 64);
            const bool wantMax = (((l & k) == 0) == ((l & jj) == 0));
            v = (wantMax == (o > v)) ? o : v;
        }
    }
    return v;
}

// cold path: 65..128 survivors -> 32 rounds of wave-argmax extraction
__device__ __noinline__ void top32_rare(const int* sj, const unsigned* sk,
                                        int sc, int l, int* sel)
{
    unsigned long long c0 = 0ull, c1 = 0ull;
    if (l < sc)
        c0 = ((unsigned long long)sk[l] << 32) | (unsigned)(~(unsigned)sj[l]);
    if (l + 64 < sc)
        c1 = ((unsigned long long)sk[l + 64] << 32) |
             (unsigned)(~(unsigned)sj[l + 64]);
    for (int r = 0; r < NK; ++r) {
        unsigned long long w = (c0 > c1) ? c0 : c1;
        #pragma unroll
        for (int off = 32; off >= 1; off >>= 1) {
            const unsigned long long o = __shfl_xor(w, off, 64);
            if (o > w) w = o;
        }
        if (c0 == w) c0 = 0ull; else if (c1 == w) c1 = 0ull;
        if (l == 0) sel[r] = (int)(~(unsigned)(w & 0xffffffffull));
    }
}

// exact top-32 among survivors by (key desc, idx asc); writes sel[0..31]
__device__ __forceinline__ void top32_sel(const int* sj, const unsigned* sk,
                                          int sc, int l, int* sel)
{
    if (sc <= 64) {
        unsigned long long comp = 0ull;       // padding sorts below all real
        if (l < sc)
            comp = ((unsigned long long)sk[l] << 32) |
                   (unsigned)(~(unsigned)sj[l]);
        #pragma unroll
        for (int k = 2; k <= 64; k <<= 1) {
            #pragma unroll
            for (int jj = k >> 1; jj >= 1; jj >>= 1) {
                const unsigned long long other = __shfl_xor(comp, jj, 64);
                const bool wantMax = (((l & k) == 0) == ((l & jj) == 0));
                comp = (wantMax == (other > comp)) ? other : comp;
            }
        }
        if (l < NK) sel[l] = (int)(~(unsigned)(comp & 0xffffffffull));
    } else {
        top32_rare(sj, sk, sc, l, sel);
    }
}

// exact re-key: uncontracted reference bits for survivors (wave-local)
__device__ __forceinline__ void rekey(const float* xb, const int* sj,
                                      unsigned* sk, int sc, int l, const QS& q)
{
    for (int s = l; s < sc; s += 64) {
        const int j = sj[s];
        const float px = xb[j];
        const float py = xb[NP + j];
        const float pz = xb[2 * NP + j];
        const float xxj   = (px * px + py * py) + pz * pz;   // no FMA (pragma)
        const float inner = (q.x * px + q.y * py) + q.z * pz;
        const float pd    = (2.0f * inner - q.xx) - xxj;
        const unsigned u  = __float_as_uint(pd);
        sk[s] = (u & 0x80000000u) ? ~u : (u | 0x80000000u);
    }
}

// mean-pool 32 selected rows -> dst[0..127] (fp32), wave-local
__device__ __forceinline__ void pool_row(const float* fb, const int* sel,
                                         int l, float* dst)
{
    const int cg = l & 31;    // channels 4*cg .. 4*cg+3
    const int rg = l >> 5;    // rows rg*16 .. rg*16+15
    float ax = 0.f, ay = 0.f, az = 0.f, aw = 0.f;
    #pragma unroll 4
    for (int k = 0; k < 16; ++k) {
        const int j = sel[rg * 16 + k] & (NP - 1);   // fault-proof mask
        const float4 f = *(const float4*)&fb[(size_t)j * NC + cg * 4];
        ax += f.x; ay += f.y; az += f.z; aw += f.w;
    }
    const float bx = __shfl_down(ax, 32, 64);
    const float by = __shfl_down(ay, 32, 64);
    const float bz = __shfl_down(az, 32, 64);
    const float bw = __shfl_down(aw, 32, 64);
    if (l < 32) {
        const float inv = 1.0f / (float)NK;
        float4 s;
        s.x = (ax + bx) * inv; s.y = (ay + by) * inv;
        s.z = (az + bz) * inv; s.w = (aw + bw) * inv;
        *(float4*)&dst[l * 4] = s;
    }
}

// ---------------------------------------------------------------------------
// Kernel A: 2 waves, FOUR queries; each wave scans half the candidates.
// Blocks 0..127 also transpose W -> Wt (128 elems each).
// ---------------------------------------------------------------------------
__global__ __launch_bounds__(128, 4) void knn_wave2_kernel(
    const float* __restrict__ xyz,    // [B,3,N]
    const float* __restrict__ feats,  // [B,N,C]
    const float* __restrict__ W,      // [C,C]
    float* __restrict__ Wt,           // [C,C] transposed out (or nullptr)
    float* __restrict__ pooled)       // [B*N, C] (d_out, fp32 temp)
{
    const int blk = blockIdx.x;       // 0 .. NB*NP/NQ-1 (4096)
    const int b   = blk >> 10;        // 1024 blocks per batch
    const int i0  = (blk & 1023) * NQ;
    const int tid = threadIdx.x;      // 0..127
    const int w   = tid >> 6;         // wave 0/1
    const int l   = tid & 63;         // lane 0..63

    // spread W-transpose over the first 128 blocks (1 coalesced read each)
    if (Wt != nullptr && blk < 128) {
        const int e = blk * 128 + tid;
        Wt[(e & (NC - 1)) * NC + (e >> 7)] = W[e];
    }

    const float* xb = xyz + (size_t)b * 3 * NP;
    const QS q0 = load_q(xb, i0 + 0);
    const QS q1 = load_q(xb, i0 + 1);
    const QS q2 = load_q(xb, i0 + 2);
    const QS q3 = load_q(xb, i0 + 3);

    const int base = w * (NP / 2);    // this wave's candidate half

    __shared__ int      s_sj[NQ][128];
    __shared__ unsigned s_sk[NQ][128];
    __shared__ float    s_mrg[NQ][64];
    __shared__ float    s_thr[NQ];
    __shared__ int      s_sel[2][NK];
    __shared__ unsigned s_cnt[NQ];

    if (tid < NQ) s_cnt[tid] = 0;

    // -- pass 1: running maxima of approx pd over this wave's 2048 cands --
    float t0 = -3.0e38f, t1 = -3.0e38f, t2 = -3.0e38f, t3 = -3.0e38f;
#define CAND1(CX, CY, CZ) {                                                   \
        const float xxj = fmaf(CX, CX, fmaf(CY, CY, CZ * CZ));                \
        t0 = fmaxf(t0, pdq(CX, CY, CZ, xxj, q0));                             \
        t1 = fmaxf(t1, pdq(CX, CY, CZ, xxj, q1));                             \
        t2 = fmaxf(t2, pdq(CX, CY, CZ, xxj, q2));                             \
        t3 = fmaxf(t3, pdq(CX, CY, CZ, xxj, q3)); }
    #pragma unroll 2
    for (int it = 0; it < 8; ++it) {
        const int j4 = base + it * 256 + l * 4;
        const float4 X = *(const float4*)&xb[j4];
        const float4 Y = *(const float4*)&xb[NP + j4];
        const float4 Z = *(const float4*)&xb[2 * NP + j4];
        CAND1(X.x, Y.x, Z.x) CAND1(X.y, Y.y, Z.y)
        CAND1(X.z, Y.z, Z.z) CAND1(X.w, Y.w, Z.w)
    }
#undef CAND1

    // per-wave sort of 64 lane-maxima; top-32 of each wave into LDS
    t0 = sort64_desc(t0, l);
    t1 = sort64_desc(t1, l);
    t2 = sort64_desc(t2, l);
    t3 = sort64_desc(t3, l);
    if (l < 32) {
        s_mrg[0][w * 32 + l] = t0;
        s_mrg[1][w * 32 + l] = t1;
        s_mrg[2][w * 32 + l] = t2;
        s_mrg[3][w * 32 + l] = t3;
    }
    __syncthreads();

    // each wave merges (full-sorts) 2 queries' merged-64; m32 = sorted[31]
    {
        const int qa = 2 * w, qb = 2 * w + 1;
        const float sa = sort64_desc(s_mrg[qa][l], l);
        const float sb = sort64_desc(s_mrg[qb][l], l);
        if (l == 31) s_thr[qa] = sa - 0x1p-11f;   // margin >= 2*delta
        if (l == 31) s_thr[qb] = sb - 0x1p-11f;
    }
    __syncthreads();

    const float thr0 = s_thr[0];
    const float thr1 = s_thr[1];
    const float thr2 = s_thr[2];
    const float thr3 = s_thr[3];

    // -- pass 2: recompute (L1-hot) and gather survivors (shared arrays) --
#define CAND2(CX, CY, CZ, JOFF) {                                             \
        const float xxj = fmaf(CX, CX, fmaf(CY, CY, CZ * CZ));                \
        const float pA = pdq(CX, CY, CZ, xxj, q0);                            \
        const float pB = pdq(CX, CY, CZ, xxj, q1);                            \
        const float pC = pdq(CX, CY, CZ, xxj, q2);                            \
        const float pD = pdq(CX, CY, CZ, xxj, q3);                            \
        if (pA >= thr0) { const unsigned p = atomicAdd(&s_cnt[0], 1u);        \
                          if (p < 128u) s_sj[0][p] = j4 + (JOFF); }           \
        if (pB >= thr1) { const unsigned p = atomicAdd(&s_cnt[1], 1u);        \
                          if (p < 128u) s_sj[1][p] = j4 + (JOFF); }           \
        if (pC >= thr2) { const unsigned p = atomicAdd(&s_cnt[2], 1u);        \
                          if (p < 128u) s_sj[2][p] = j4 + (JOFF); }           \
        if (pD >= thr3) { const unsigned p = atomicAdd(&s_cnt[3], 1u);        \
                          if (p < 128u) s_sj[3][p] = j4 + (JOFF); } }
    #pragma unroll 2
    for (int it = 0; it < 8; ++it) {
        const int j4 = base + it * 256 + l * 4;
        const float4 X = *(const float4*)&xb[j4];
        const float4 Y = *(const float4*)&xb[NP + j4];
        const float4 Z = *(const float4*)&xb[2 * NP + j4];
        CAND2(X.x, Y.x, Z.x, 0) CAND2(X.y, Y.y, Z.y, 1)
        CAND2(X.z, Y.z, Z.z, 2) CAND2(X.w, Y.w, Z.w, 3)
    }
#undef CAND2
    __syncthreads();

    const float* fb = feats + (size_t)b * NP * NC;

    // -- epilogue: wave 0 -> queries 0,1; wave 1 -> queries 2,3 (wave-local)
#define EPI(QI, QREF) {                                                       \
        const int sc = (int)min(s_cnt[QI], 128u);                             \
        rekey(xb, s_sj[QI], s_sk[QI], sc, l, QREF);                           \
        top32_sel(s_sj[QI], s_sk[QI], sc, l, s_sel[w]);                       \
        pool_row(fb, s_sel[w], l,                                             \
                 pooled + (size_t)((b << 12) | (i0 + QI)) * NC); }
    if (w == 0) { EPI(0, q0) EPI(1, q1) }
    else        { EPI(2, q2) EPI(3, q3) }
#undef EPI
}

// ---------------------------------------------------------------------------
// Kernel B (v3, r17-verbatim): in-place Linear, 512 blocks x 32 rows.
// ---------------------------------------------------------------------------
constexpr int LROWS = 32;
__global__ __launch_bounds__(NT) void linear_v3_kernel(
    float* __restrict__ io,           // [B*N, C] fp32, in-place
    const float* __restrict__ Wt)     // [C, C] transposed: Wt[c][d]
{
    const int t    = threadIdx.x;
    const int row0 = blockIdx.x * LROWS;

    __shared__ float P[LROWS * NC];   // 16 KiB

    const float4* src4 = (const float4*)(io + (size_t)row0 * NC);
    #pragma unroll
    for (int m = 0; m < 4; ++m)
        ((float4*)P)[m * NT + t] = src4[m * NT + t];
    __syncthreads();

    const int dg = t & 31;            // d = 4*dg .. 4*dg+3
    const int rg = t >> 5;            // rows 4*rg .. 4*rg+3

    float4 a0 = make_float4(0.f,0.f,0.f,0.f);
    float4 a1 = make_float4(0.f,0.f,0.f,0.f);
    float4 a2 = make_float4(0.f,0.f,0.f,0.f);
    float4 a3 = make_float4(0.f,0.f,0.f,0.f);
    const float4* Wt4 = (const float4*)Wt;   // row c = 32 float4
    const float*  Pr  = P + rg * 4 * NC;

#define LSTEP(K, PC)                                                          \
    {                                                                         \
        const float4 w = Wt4[(c4 * 4 + K) * 32 + dg];                         \
        a0.x = fmaf(p0.PC, w.x, a0.x); a0.y = fmaf(p0.PC, w.y, a0.y);         \
        a0.z = fmaf(p0.PC, w.z, a0.z); a0.w = fmaf(p0.PC, w.w, a0.w);         \
        a1.x = fmaf(p1.PC, w.x, a1.x); a1.y = fmaf(p1.PC, w.y, a1.y);         \
        a1.z = fmaf(p1.PC, w.z, a1.z); a1.w = fmaf(p1.PC, w.w, a1.w);         \
        a2.x = fmaf(p2.PC, w.x, a2.x); a2.y = fmaf(p2.PC, w.y, a2.y);         \
        a2.z = fmaf(p2.PC, w.z, a2.z); a2.w = fmaf(p2.PC, w.w, a2.w);         \
        a3.x = fmaf(p3.PC, w.x, a3.x); a3.y = fmaf(p3.PC, w.y, a3.y);         \
        a3.z = fmaf(p3.PC, w.z, a3.z); a3.w = fmaf(p3.PC, w.w, a3.w);         \
    }

    #pragma unroll 4
    for (int c4 = 0; c4 < NC / 4; ++c4) {
        const float4 p0 = *(const float4*)&Pr[c4 * 4];            // b128 reads
        const float4 p1 = *(const float4*)&Pr[NC + c4 * 4];
        const float4 p2 = *(const float4*)&Pr[2 * NC + c4 * 4];
        const float4 p3 = *(const float4*)&Pr[3 * NC + c4 * 4];
        LSTEP(0, x) LSTEP(1, y) LSTEP(2, z) LSTEP(3, w)
    }
#undef LSTEP

    float4* dst4 = (float4*)(io + (size_t)row0 * NC);
    const int r4 = rg * 4;
    dst4[(r4 + 0) * 32 + dg] = a0;    // all staging reads done pre-barrier
    dst4[(r4 + 1) * 32 + dg] = a1;
    dst4[(r4 + 2) * 32 + dg] = a2;
    dst4[(r4 + 3) * 32 + dg] = a3;
}

// ---------------------------------------------------------------------------
// Fallback (ws-less): old 64-row in-place linear reading W directly.
// ---------------------------------------------------------------------------
__global__ __launch_bounds__(NT) void linear_kernel(
    float* __restrict__ io, const float* __restrict__ W)
{
    const int t = threadIdx.x;
    const int row0 = blockIdx.x * 64;
    __shared__ float P[64 * NC];
    const float* src = io + (size_t)row0 * NC;
    #pragma unroll
    for (int m = 0; m < 8; ++m) {
        const int e4 = m * NT + t;
        *(float4*)&P[e4 * 4] = *(const float4*)&src[e4 * 4];
    }
    __syncthreads();
    const int d = t & (NC - 1);
    const int rbase = (t >> 7) * 32;
    float acc[32];
    #pragma unroll
    for (int k = 0; k < 32; ++k) acc[k] = 0.f;
    const float* Wd = W + (size_t)d * NC;
    for (int c4 = 0; c4 < NC / 4; ++c4) {
        const float4 w = *(const float4*)(Wd + c4 * 4);
        #pragma unroll
        for (int k = 0; k < 32; ++k) {
            const float4 pv = *(const float4*)&P[(rbase + k) * NC + c4 * 4];
            acc[k] = fmaf(pv.x, w.x, acc[k]);
            acc[k] = fmaf(pv.y, w.y, acc[k]);
            acc[k] = fmaf(pv.z, w.z, acc[k]);
            acc[k] = fmaf(pv.w, w.w, acc[k]);
        }
    }
    #pragma unroll
    for (int k = 0; k < 32; ++k)
        io[(size_t)(row0 + rbase + k) * NC + d] = acc[k];
}

// ---------------------------------------------------------------------------
extern "C" void kernel_launch(void* const* d_in, const int* in_sizes, int n_in,
                              void* d_out, int out_size, void* d_ws, size_t ws_size,
                              hipStream_t stream) {
    const float* xyz   = nullptr;  // 49152
    const float* feats = nullptr;  // 2097152
    const float* W     = nullptr;  // 16384
    for (int k = 0; k < n_in; ++k) {
        if      (in_sizes[k] == NB * 3 * NP)       xyz   = (const float*)d_in[k];
        else if (in_sizes[k] == NB * NP * NC)      feats = (const float*)d_in[k];
        else if (in_sizes[k] == NC * NC)           W     = (const float*)d_in[k];
    }
    float* out = (float*)d_out;

    const size_t need = sizeof(float) * (size_t)(NC * NC);
    if (ws_size >= need) {
        float* Wt = (float*)d_ws;                  // 64 KiB
        knn_wave2_kernel<<<NB * NP / NQ, 128, 0, stream>>>(xyz, feats, W, Wt, out);
        linear_v3_kernel<<<NB * NP / LROWS, NT, 0, stream>>>(out, Wt);
    } else {
        knn_wave2_kernel<<<NB * NP / NQ, 128, 0, stream>>>(xyz, feats, W, nullptr, out);
        linear_kernel<<<NB * NP / 64, NT, 0, stream>>>(out, W);
    }
}

// Round 23
// 72.993 us; speedup vs baseline: 1.3775x; 1.0295x over previous
//
#include <hip/hip_runtime.h>
#include <hip/hip_bf16.h>

// Forbid FMA contraction for plain fp expressions in ALL device code below:
// the kNN ranking must bit-match the reference's uncontracted fp32 expression
//   pd[i,j] = 2*inner(i,j) - xx[i] - xx[j]
// (rounds 4/6/8/10/11/13/14/16/17/18/19/21/22 passed uncontracted; round 5
// regressed when the compiler fused 2*inner-xxi into v_fma_f32). Explicit
// fmaf() calls are NOT affected -- the approx prefilter exploits that.
#pragma clang fp contract(off)

// B=4, N=4096, C=128, K=32. All fp32. top-K LARGEST pd, tie -> lowest index.
// Round 23 (r22 structure kept):
//   - knn approx filter uses folded weights: pd = fmaf(2qx,x, fmaf(2qy,y,
//     fmaf(2qz,z, -xxj))) - xxi -> 4 ops/query vs 6 (-15% main-loop VALU).
//     w2=q+q exact; approx err <=5e-5 << 2^-11 margin; EXACT re-key
//     untouched (qx = 0.5*wx, exact) => output bits unchanged.
//   - linear_v4: full 64KB Wt staged in LDS (80KB total -> 2 blocks/CU,
//     same occupancy as v3) -- v3 was L2-latency-bound on 128 Wt loads/thread
//     at 2 waves/SIMD (13-14us vs 4.3us VALU floor). ds_read_b128 kills the
//     latency. Same ascending-c fma order -> bit-identical output.
// Spill tripwire: WRITE_SIZE (r18 lesson).

constexpr int NB   = 4;
constexpr int NP   = 4096;
constexpr int NC   = 128;
constexpr int NK   = 32;
constexpr int NT   = 256;   // linear kernel block size
constexpr int NQ   = 4;     // queries per block

struct QS { float wx, wy, wz, xx; };   // wx=2qx etc (exact), xx uncontracted

__device__ __forceinline__ QS load_q(const float* xb, int i) {
    const float x = xb[i];
    const float y = xb[NP + i];
    const float z = xb[2 * NP + i];
    QS q;
    q.xx = (x * x + y * y) + z * z;   // uncontracted (exact reference bits)
    q.wx = x + x; q.wy = y + y; q.wz = z + z;   // exact doubling
    return q;
}

// approx pd (fmaf allowed; bounded vs exact by delta <= ~5e-5)
__device__ __forceinline__ float pdq(float x, float y, float z, float xxj,
                                     const QS& q)
{
    return fmaf(q.wx, x, fmaf(q.wy, y, fmaf(q.wz, z, -xxj))) - q.xx;
}

// 64-lane bitonic sort (desc); returns this lane's sorted value
__device__ __forceinline__ float sort64_desc(float v, int l) {
    #pragma unroll
    for (int k = 2; k <= 64; k <<= 1) {
        #pragma unroll
        for (int jj = k >> 1; jj >= 1; jj >>= 1) {
            const float o = __shfl_xor(v, jj, 64);
            const bool wantMax = (((l & k) == 0) == ((l & jj) == 0));
            v = (wantMax == (o > v)) ? o : v;
        }
    }
    return v;
}

// cold path: 65..128 survivors -> 32 rounds of wave-argmax extraction
__device__ __noinline__ void top32_rare(const int* sj, const unsigned* sk,
                                        int sc, int l, int* sel)
{
    unsigned long long c0 = 0ull, c1 = 0ull;
    if (l < sc)
        c0 = ((unsigned long long)sk[l] << 32) | (unsigned)(~(unsigned)sj[l]);
    if (l + 64 < sc)
        c1 = ((unsigned long long)sk[l + 64] << 32) |
             (unsigned)(~(unsigned)sj[l + 64]);
    for (int r = 0; r < NK; ++r) {
        unsigned long long w = (c0 > c1) ? c0 : c1;
        #pragma unroll
        for (int off = 32; off >= 1; off >>= 1) {
            const unsigned long long o = __shfl_xor(w, off, 64);
            if (o > w) w = o;
        }
        if (c0 == w) c0 = 0ull; else if (c1 == w) c1 = 0ull;
        if (l == 0) sel[r] = (int)(~(unsigned)(w & 0xffffffffull));
    }
}

// exact top-32 among survivors by (key desc, idx asc); writes sel[0..31]
__device__ __forceinline__ void top32_sel(const int* sj, const unsigned* sk,
                                          int sc, int l, int* sel)
{
    if (sc <= 64) {
        unsigned long long comp = 0ull;       // padding sorts below all real
        if (l < sc)
            comp = ((unsigned long long)sk[l] << 32) |
                   (unsigned)(~(unsigned)sj[l]);
        #pragma unroll
        for (int k = 2; k <= 64; k <<= 1) {
            #pragma unroll
            for (int jj = k >> 1; jj >= 1; jj >>= 1) {
                const unsigned long long other = __shfl_xor(comp, jj, 64);
                const bool wantMax = (((l & k) == 0) == ((l & jj) == 0));
                comp = (wantMax == (other > comp)) ? other : comp;
            }
        }
        if (l < NK) sel[l] = (int)(~(unsigned)(comp & 0xffffffffull));
    } else {
        top32_rare(sj, sk, sc, l, sel);
    }
}

// exact re-key: uncontracted reference bits for survivors (wave-local)
__device__ __forceinline__ void rekey(const float* xb, const int* sj,
                                      unsigned* sk, int sc, int l, const QS& q)
{
    const float qx = 0.5f * q.wx;     // exact (power-of-2 scale)
    const float qy = 0.5f * q.wy;
    const float qz = 0.5f * q.wz;
    for (int s = l; s < sc; s += 64) {
        const int j = sj[s];
        const float px = xb[j];
        const float py = xb[NP + j];
        const float pz = xb[2 * NP + j];
        const float xxj   = (px * px + py * py) + pz * pz;   // no FMA (pragma)
        const float inner = (qx * px + qy * py) + qz * pz;
        const float pd    = (2.0f * inner - q.xx) - xxj;
        const unsigned u  = __float_as_uint(pd);
        sk[s] = (u & 0x80000000u) ? ~u : (u | 0x80000000u);
    }
}

// mean-pool 32 selected rows -> dst[0..127] (fp32), wave-local
__device__ __forceinline__ void pool_row(const float* fb, const int* sel,
                                         int l, float* dst)
{
    const int cg = l & 31;    // channels 4*cg .. 4*cg+3
    const int rg = l >> 5;    // rows rg*16 .. rg*16+15
    float ax = 0.f, ay = 0.f, az = 0.f, aw = 0.f;
    #pragma unroll 4
    for (int k = 0; k < 16; ++k) {
        const int j = sel[rg * 16 + k] & (NP - 1);   // fault-proof mask
        const float4 f = *(const float4*)&fb[(size_t)j * NC + cg * 4];
        ax += f.x; ay += f.y; az += f.z; aw += f.w;
    }
    const float bx = __shfl_down(ax, 32, 64);
    const float by = __shfl_down(ay, 32, 64);
    const float bz = __shfl_down(az, 32, 64);
    const float bw = __shfl_down(aw, 32, 64);
    if (l < 32) {
        const float inv = 1.0f / (float)NK;
        float4 s;
        s.x = (ax + bx) * inv; s.y = (ay + by) * inv;
        s.z = (az + bz) * inv; s.w = (aw + bw) * inv;
        *(float4*)&dst[l * 4] = s;
    }
}

// ---------------------------------------------------------------------------
// Kernel A: 2 waves, FOUR queries; each wave scans half the candidates.
// Blocks 0..127 also transpose W -> Wt (128 elems each).
// ---------------------------------------------------------------------------
__global__ __launch_bounds__(128, 4) void knn_wave2_kernel(
    const float* __restrict__ xyz,    // [B,3,N]
    const float* __restrict__ feats,  // [B,N,C]
    const float* __restrict__ W,      // [C,C]
    float* __restrict__ Wt,           // [C,C] transposed out (or nullptr)
    float* __restrict__ pooled)       // [B*N, C] (d_out, fp32 temp)
{
    const int blk = blockIdx.x;       // 0 .. NB*NP/NQ-1 (4096)
    const int b   = blk >> 10;        // 1024 blocks per batch
    const int i0  = (blk & 1023) * NQ;
    const int tid = threadIdx.x;      // 0..127
    const int w   = tid >> 6;         // wave 0/1
    const int l   = tid & 63;         // lane 0..63

    // spread W-transpose over the first 128 blocks (1 coalesced read each)
    if (Wt != nullptr && blk < 128) {
        const int e = blk * 128 + tid;
        Wt[(e & (NC - 1)) * NC + (e >> 7)] = W[e];
    }

    const float* xb = xyz + (size_t)b * 3 * NP;
    const QS q0 = load_q(xb, i0 + 0);
    const QS q1 = load_q(xb, i0 + 1);
    const QS q2 = load_q(xb, i0 + 2);
    const QS q3 = load_q(xb, i0 + 3);

    const int base = w * (NP / 2);    // this wave's candidate half

    __shared__ int      s_sj[NQ][128];
    __shared__ unsigned s_sk[NQ][128];
    __shared__ float    s_mrg[NQ][64];
    __shared__ float    s_thr[NQ];
    __shared__ int      s_sel[2][NK];
    __shared__ unsigned s_cnt[NQ];

    if (tid < NQ) s_cnt[tid] = 0;

    // -- pass 1: running maxima of approx pd over this wave's 2048 cands --
    float t0 = -3.0e38f, t1 = -3.0e38f, t2 = -3.0e38f, t3 = -3.0e38f;
#define CAND1(CX, CY, CZ) {                                                   \
        const float xxj = fmaf(CX, CX, fmaf(CY, CY, CZ * CZ));                \
        t0 = fmaxf(t0, pdq(CX, CY, CZ, xxj, q0));                             \
        t1 = fmaxf(t1, pdq(CX, CY, CZ, xxj, q1));                             \
        t2 = fmaxf(t2, pdq(CX, CY, CZ, xxj, q2));                             \
        t3 = fmaxf(t3, pdq(CX, CY, CZ, xxj, q3)); }
    #pragma unroll 2
    for (int it = 0; it < 8; ++it) {
        const int j4 = base + it * 256 + l * 4;
        const float4 X = *(const float4*)&xb[j4];
        const float4 Y = *(const float4*)&xb[NP + j4];
        const float4 Z = *(const float4*)&xb[2 * NP + j4];
        CAND1(X.x, Y.x, Z.x) CAND1(X.y, Y.y, Z.y)
        CAND1(X.z, Y.z, Z.z) CAND1(X.w, Y.w, Z.w)
    }
#undef CAND1

    // per-wave sort of 64 lane-maxima; top-32 of each wave into LDS
    t0 = sort64_desc(t0, l);
    t1 = sort64_desc(t1, l);
    t2 = sort64_desc(t2, l);
    t3 = sort64_desc(t3, l);
    if (l < 32) {
        s_mrg[0][w * 32 + l] = t0;
        s_mrg[1][w * 32 + l] = t1;
        s_mrg[2][w * 32 + l] = t2;
        s_mrg[3][w * 32 + l] = t3;
    }
    __syncthreads();

    // each wave merges (full-sorts) 2 queries' merged-64; m32 = sorted[31]
    {
        const int qa = 2 * w, qb = 2 * w + 1;
        const float sa = sort64_desc(s_mrg[qa][l], l);
        const float sb = sort64_desc(s_mrg[qb][l], l);
        if (l == 31) s_thr[qa] = sa - 0x1p-11f;   // margin >= 2*delta
        if (l == 31) s_thr[qb] = sb - 0x1p-11f;
    }
    __syncthreads();

    const float thr0 = s_thr[0];
    const float thr1 = s_thr[1];
    const float thr2 = s_thr[2];
    const float thr3 = s_thr[3];

    // -- pass 2: recompute (L1-hot) and gather survivors (shared arrays) --
#define CAND2(CX, CY, CZ, JOFF) {                                             \
        const float xxj = fmaf(CX, CX, fmaf(CY, CY, CZ * CZ));                \
        const float pA = pdq(CX, CY, CZ, xxj, q0);                            \
        const float pB = pdq(CX, CY, CZ, xxj, q1);                            \
        const float pC = pdq(CX, CY, CZ, xxj, q2);                            \
        const float pD = pdq(CX, CY, CZ, xxj, q3);                            \
        if (pA >= thr0) { const unsigned p = atomicAdd(&s_cnt[0], 1u);        \
                          if (p < 128u) s_sj[0][p] = j4 + (JOFF); }           \
        if (pB >= thr1) { const unsigned p = atomicAdd(&s_cnt[1], 1u);        \
                          if (p < 128u) s_sj[1][p] = j4 + (JOFF); }           \
        if (pC >= thr2) { const unsigned p = atomicAdd(&s_cnt[2], 1u);        \
                          if (p < 128u) s_sj[2][p] = j4 + (JOFF); }           \
        if (pD >= thr3) { const unsigned p = atomicAdd(&s_cnt[3], 1u);        \
                          if (p < 128u) s_sj[3][p] = j4 + (JOFF); } }
    #pragma unroll 2
    for (int it = 0; it < 8; ++it) {
        const int j4 = base + it * 256 + l * 4;
        const float4 X = *(const float4*)&xb[j4];
        const float4 Y = *(const float4*)&xb[NP + j4];
        const float4 Z = *(const float4*)&xb[2 * NP + j4];
        CAND2(X.x, Y.x, Z.x, 0) CAND2(X.y, Y.y, Z.y, 1)
        CAND2(X.z, Y.z, Z.z, 2) CAND2(X.w, Y.w, Z.w, 3)
    }
#undef CAND2
    __syncthreads();

    const float* fb = feats + (size_t)b * NP * NC;

    // -- epilogue: wave 0 -> queries 0,1; wave 1 -> queries 2,3 (wave-local)
#define EPI(QI, QREF) {                                                       \
        const int sc = (int)min(s_cnt[QI], 128u);                             \
        rekey(xb, s_sj[QI], s_sk[QI], sc, l, QREF);                           \
        top32_sel(s_sj[QI], s_sk[QI], sc, l, s_sel[w]);                       \
        pool_row(fb, s_sel[w], l,                                             \
                 pooled + (size_t)((b << 12) | (i0 + QI)) * NC); }
    if (w == 0) { EPI(0, q0) EPI(1, q1) }
    else        { EPI(2, q2) EPI(3, q3) }
#undef EPI
}

// ---------------------------------------------------------------------------
// Kernel B (v4): in-place Linear, 512 blocks x 32 rows, full Wt in LDS.
// v3 was L2-latency-bound on per-thread Wt loads (2 waves/SIMD can't hide
// ~200cy); staging Wt once per block (80KB LDS total -> still 2 blocks/CU)
// converts them to ds_read_b128. Same ascending-c fma order as v2/v3 ->
// bit-identical output.
// ---------------------------------------------------------------------------
constexpr int LROWS = 32;
__global__ __launch_bounds__(NT) void linear_v4_kernel(
    float* __restrict__ io,           // [B*N, C] fp32, in-place
    const float* __restrict__ Wt)     // [C, C] transposed: Wt[c][d]
{
    const int t    = threadIdx.x;
    const int row0 = blockIdx.x * LROWS;

    __shared__ float  P[LROWS * NC];  // 16 KiB
    __shared__ float4 sWt[NC * 32];   // 64 KiB: row c = 32 float4

    const float4* src4 = (const float4*)(io + (size_t)row0 * NC);
    #pragma unroll
    for (int m = 0; m < 4; ++m)
        ((float4*)P)[m * NT + t] = src4[m * NT + t];
    const float4* Wt4g = (const float4*)Wt;
    #pragma unroll
    for (int m = 0; m < 16; ++m)
        sWt[m * NT + t] = Wt4g[m * NT + t];       // coalesced 64KB stage
    __syncthreads();

    const int dg = t & 31;            // d = 4*dg .. 4*dg+3
    const int rg = t >> 5;            // rows 4*rg .. 4*rg+3

    float4 a0 = make_float4(0.f,0.f,0.f,0.f);
    float4 a1 = make_float4(0.f,0.f,0.f,0.f);
    float4 a2 = make_float4(0.f,0.f,0.f,0.f);
    float4 a3 = make_float4(0.f,0.f,0.f,0.f);
    const float* Pr = P + rg * 4 * NC;

#define LSTEP(K, PC)                                                          \
    {                                                                         \
        const float4 w = sWt[(c4 * 4 + K) * 32 + dg];                         \
        a0.x = fmaf(p0.PC, w.x, a0.x); a0.y = fmaf(p0.PC, w.y, a0.y);         \
        a0.z = fmaf(p0.PC, w.z, a0.z); a0.w = fmaf(p0.PC, w.w, a0.w);         \
        a1.x = fmaf(p1.PC, w.x, a1.x); a1.y = fmaf(p1.PC, w.y, a1.y);         \
        a1.z = fmaf(p1.PC, w.z, a1.z); a1.w = fmaf(p1.PC, w.w, a1.w);         \
        a2.x = fmaf(p2.PC, w.x, a2.x); a2.y = fmaf(p2.PC, w.y, a2.y);         \
        a2.z = fmaf(p2.PC, w.z, a2.z); a2.w = fmaf(p2.PC, w.w, a2.w);         \
        a3.x = fmaf(p3.PC, w.x, a3.x); a3.y = fmaf(p3.PC, w.y, a3.y);         \
        a3.z = fmaf(p3.PC, w.z, a3.z); a3.w = fmaf(p3.PC, w.w, a3.w);         \
    }

    #pragma unroll 4
    for (int c4 = 0; c4 < NC / 4; ++c4) {
        const float4 p0 = *(const float4*)&Pr[c4 * 4];            // b128 reads
        const float4 p1 = *(const float4*)&Pr[NC + c4 * 4];
        const float4 p2 = *(const float4*)&Pr[2 * NC + c4 * 4];
        const float4 p3 = *(const float4*)&Pr[3 * NC + c4 * 4];
        LSTEP(0, x) LSTEP(1, y) LSTEP(2, z) LSTEP(3, w)
    }
#undef LSTEP

    float4* dst4 = (float4*)(io + (size_t)row0 * NC);
    const int r4 = rg * 4;
    dst4[(r4 + 0) * 32 + dg] = a0;    // all staging reads done pre-barrier
    dst4[(r4 + 1) * 32 + dg] = a1;
    dst4[(r4 + 2) * 32 + dg] = a2;
    dst4[(r4 + 3) * 32 + dg] = a3;
}

// ---------------------------------------------------------------------------
// Fallback (ws-less): old 64-row in-place linear reading W directly.
// ---------------------------------------------------------------------------
__global__ __launch_bounds__(NT) void linear_kernel(
    float* __restrict__ io, const float* __restrict__ W)
{
    const int t = threadIdx.x;
    const int row0 = blockIdx.x * 64;
    __shared__ float P[64 * NC];
    const float* src = io + (size_t)row0 * NC;
    #pragma unroll
    for (int m = 0; m < 8; ++m) {
        const int e4 = m * NT + t;
        *(float4*)&P[e4 * 4] = *(const float4*)&src[e4 * 4];
    }
    __syncthreads();
    const int d = t & (NC - 1);
    const int rbase = (t >> 7) * 32;
    float acc[32];
    #pragma unroll
    for (int k = 0; k < 32; ++k) acc[k] = 0.f;
    const float* Wd = W + (size_t)d * NC;
    for (int c4 = 0; c4 < NC / 4; ++c4) {
        const float4 w = *(const float4*)(Wd + c4 * 4);
        #pragma unroll
        for (int k = 0; k < 32; ++k) {
            const float4 pv = *(const float4*)&P[(rbase + k) * NC + c4 * 4];
            acc[k] = fmaf(pv.x, w.x, acc[k]);
            acc[k] = fmaf(pv.y, w.y, acc[k]);
            acc[k] = fmaf(pv.z, w.z, acc[k]);
            acc[k] = fmaf(pv.w, w.w, acc[k]);
        }
    }
    #pragma unroll
    for (int k = 0; k < 32; ++k)
        io[(size_t)(row0 + rbase + k) * NC + d] = acc[k];
}

// ---------------------------------------------------------------------------
extern "C" void kernel_launch(void* const* d_in, const int* in_sizes, int n_in,
                              void* d_out, int out_size, void* d_ws, size_t ws_size,
                              hipStream_t stream) {
    const float* xyz   = nullptr;  // 49152
    const float* feats = nullptr;  // 2097152
    const float* W     = nullptr;  // 16384
    for (int k = 0; k < n_in; ++k) {
        if      (in_sizes[k] == NB * 3 * NP)       xyz   = (const float*)d_in[k];
        else if (in_sizes[k] == NB * NP * NC)      feats = (const float*)d_in[k];
        else if (in_sizes[k] == NC * NC)           W     = (const float*)d_in[k];
    }
    float* out = (float*)d_out;

    const size_t need = sizeof(float) * (size_t)(NC * NC);
    if (ws_size >= need) {
        float* Wt = (float*)d_ws;                  // 64 KiB
        knn_wave2_kernel<<<NB * NP / NQ, 128, 0, stream>>>(xyz, feats, W, Wt, out);
        linear_v4_kernel<<<NB * NP / LROWS, NT, 0, stream>>>(out, Wt);
    } else {
        knn_wave2_kernel<<<NB * NP / NQ, 128, 0, stream>>>(xyz, feats, W, nullptr, out);
        linear_kernel<<<NB * NP / 64, NT, 0, stream>>>(out, W);
    }
}

// Round 24
// 62.123 us; speedup vs baseline: 1.6185x; 1.1750x over previous
//
#include <hip/hip_runtime.h>
#include <hip/hip_bf16.h>

// Forbid FMA contraction for plain fp expressions in ALL device code below:
// the kNN ranking must bit-match the reference's uncontracted fp32 expression
//   pd[i,j] = 2*inner(i,j) - xx[i] - xx[j]
// (rounds 4/6/8/10/11/13/14/16/17/18/19/21/22/23 passed uncontracted; round 5
// regressed when the compiler fused 2*inner-xxi into v_fma_f32). Explicit
// fmaf() calls are NOT affected -- the approx prefilter exploits that.
#pragma clang fp contract(off)

// B=4, N=4096, C=128, K=32. All fp32. top-K LARGEST pd, tie -> lowest index.
// Round 24: RECOMBINATION of the proven halves. r23 split: linear_v4 (Wt in
// LDS) delivered (~13.5 -> ~5us) but the folded-weight knn REGRESSED
// (54.3 -> 62.1us; VGPR 32->40, occ 60->45% -- the r9/r12/r20 occupancy
// cliff again, plus a longer serial fmaf chain hurting ILP). This round:
// r22's knn VERBATIM (32 VGPR, 54.3us proven) + r23's linear_v4 VERBATIM.
// No new mechanisms.

constexpr int NB   = 4;
constexpr int NP   = 4096;
constexpr int NC   = 128;
constexpr int NK   = 32;
constexpr int NT   = 256;   // linear kernel block size
constexpr int NQ   = 4;     // queries per block

struct QS { float x, y, z, xx; };

__device__ __forceinline__ QS load_q(const float* xb, int i) {
    QS q;
    q.x = xb[i]; q.y = xb[NP + i]; q.z = xb[2 * NP + i];
    q.xx = (q.x * q.x + q.y * q.y) + q.z * q.z;   // uncontracted (exact)
    return q;
}

// approx pd (fmaf allowed; bounded vs exact by delta <= 1e-4)
__device__ __forceinline__ float pdq(float x, float y, float z, float xxj,
                                     const QS& q)
{
    const float inner = fmaf(q.x, x, fmaf(q.y, y, q.z * z));
    return fmaf(2.0f, inner, -q.xx) - xxj;
}

// 64-lane bitonic sort (desc); returns this lane's sorted value
__device__ __forceinline__ float sort64_desc(float v, int l) {
    #pragma unroll
    for (int k = 2; k <= 64; k <<= 1) {
        #pragma unroll
        for (int jj = k >> 1; jj >= 1; jj >>= 1) {
            const float o = __shfl_xor(v, jj, 64);
            const bool wantMax = (((l & k) == 0) == ((l & jj) == 0));
            v = (wantMax == (o > v)) ? o : v;
        }
    }
    return v;
}

// cold path: 65..128 survivors -> 32 rounds of wave-argmax extraction
__device__ __noinline__ void top32_rare(const int* sj, const unsigned* sk,
                                        int sc, int l, int* sel)
{
    unsigned long long c0 = 0ull, c1 = 0ull;
    if (l < sc)
        c0 = ((unsigned long long)sk[l] << 32) | (unsigned)(~(unsigned)sj[l]);
    if (l + 64 < sc)
        c1 = ((unsigned long long)sk[l + 64] << 32) |
             (unsigned)(~(unsigned)sj[l + 64]);
    for (int r = 0; r < NK; ++r) {
        unsigned long long w = (c0 > c1) ? c0 : c1;
        #pragma unroll
        for (int off = 32; off >= 1; off >>= 1) {
            const unsigned long long o = __shfl_xor(w, off, 64);
            if (o > w) w = o;
        }
        if (c0 == w) c0 = 0ull; else if (c1 == w) c1 = 0ull;
        if (l == 0) sel[r] = (int)(~(unsigned)(w & 0xffffffffull));
    }
}

// exact top-32 among survivors by (key desc, idx asc); writes sel[0..31]
__device__ __forceinline__ void top32_sel(const int* sj, const unsigned* sk,
                                          int sc, int l, int* sel)
{
    if (sc <= 64) {
        unsigned long long comp = 0ull;       // padding sorts below all real
        if (l < sc)
            comp = ((unsigned long long)sk[l] << 32) |
                   (unsigned)(~(unsigned)sj[l]);
        #pragma unroll
        for (int k = 2; k <= 64; k <<= 1) {
            #pragma unroll
            for (int jj = k >> 1; jj >= 1; jj >>= 1) {
                const unsigned long long other = __shfl_xor(comp, jj, 64);
                const bool wantMax = (((l & k) == 0) == ((l & jj) == 0));
                comp = (wantMax == (other > comp)) ? other : comp;
            }
        }
        if (l < NK) sel[l] = (int)(~(unsigned)(comp & 0xffffffffull));
    } else {
        top32_rare(sj, sk, sc, l, sel);
    }
}

// exact re-key: uncontracted reference bits for survivors (wave-local)
__device__ __forceinline__ void rekey(const float* xb, const int* sj,
                                      unsigned* sk, int sc, int l, const QS& q)
{
    for (int s = l; s < sc; s += 64) {
        const int j = sj[s];
        const float px = xb[j];
        const float py = xb[NP + j];
        const float pz = xb[2 * NP + j];
        const float xxj   = (px * px + py * py) + pz * pz;   // no FMA (pragma)
        const float inner = (q.x * px + q.y * py) + q.z * pz;
        const float pd    = (2.0f * inner - q.xx) - xxj;
        const unsigned u  = __float_as_uint(pd);
        sk[s] = (u & 0x80000000u) ? ~u : (u | 0x80000000u);
    }
}

// mean-pool 32 selected rows -> dst[0..127] (fp32), wave-local
__device__ __forceinline__ void pool_row(const float* fb, const int* sel,
                                         int l, float* dst)
{
    const int cg = l & 31;    // channels 4*cg .. 4*cg+3
    const int rg = l >> 5;    // rows rg*16 .. rg*16+15
    float ax = 0.f, ay = 0.f, az = 0.f, aw = 0.f;
    #pragma unroll 4
    for (int k = 0; k < 16; ++k) {
        const int j = sel[rg * 16 + k] & (NP - 1);   // fault-proof mask
        const float4 f = *(const float4*)&fb[(size_t)j * NC + cg * 4];
        ax += f.x; ay += f.y; az += f.z; aw += f.w;
    }
    const float bx = __shfl_down(ax, 32, 64);
    const float by = __shfl_down(ay, 32, 64);
    const float bz = __shfl_down(az, 32, 64);
    const float bw = __shfl_down(aw, 32, 64);
    if (l < 32) {
        const float inv = 1.0f / (float)NK;
        float4 s;
        s.x = (ax + bx) * inv; s.y = (ay + by) * inv;
        s.z = (az + bz) * inv; s.w = (aw + bw) * inv;
        *(float4*)&dst[l * 4] = s;
    }
}

// ---------------------------------------------------------------------------
// Kernel A (r22-verbatim): 2 waves, FOUR queries; each wave scans half the
// candidates. Blocks 0..127 also transpose W -> Wt (128 elems each).
// ---------------------------------------------------------------------------
__global__ __launch_bounds__(128, 4) void knn_wave2_kernel(
    const float* __restrict__ xyz,    // [B,3,N]
    const float* __restrict__ feats,  // [B,N,C]
    const float* __restrict__ W,      // [C,C]
    float* __restrict__ Wt,           // [C,C] transposed out (or nullptr)
    float* __restrict__ pooled)       // [B*N, C] (d_out, fp32 temp)
{
    const int blk = blockIdx.x;       // 0 .. NB*NP/NQ-1 (4096)
    const int b   = blk >> 10;        // 1024 blocks per batch
    const int i0  = (blk & 1023) * NQ;
    const int tid = threadIdx.x;      // 0..127
    const int w   = tid >> 6;         // wave 0/1
    const int l   = tid & 63;         // lane 0..63

    // spread W-transpose over the first 128 blocks (1 coalesced read each)
    if (Wt != nullptr && blk < 128) {
        const int e = blk * 128 + tid;
        Wt[(e & (NC - 1)) * NC + (e >> 7)] = W[e];
    }

    const float* xb = xyz + (size_t)b * 3 * NP;
    const QS q0 = load_q(xb, i0 + 0);
    const QS q1 = load_q(xb, i0 + 1);
    const QS q2 = load_q(xb, i0 + 2);
    const QS q3 = load_q(xb, i0 + 3);

    const int base = w * (NP / 2);    // this wave's candidate half

    __shared__ int      s_sj[NQ][128];
    __shared__ unsigned s_sk[NQ][128];
    __shared__ float    s_mrg[NQ][64];
    __shared__ float    s_thr[NQ];
    __shared__ int      s_sel[2][NK];
    __shared__ unsigned s_cnt[NQ];

    if (tid < NQ) s_cnt[tid] = 0;

    // -- pass 1: running maxima of approx pd over this wave's 2048 cands --
    float t0 = -3.0e38f, t1 = -3.0e38f, t2 = -3.0e38f, t3 = -3.0e38f;
#define CAND1(CX, CY, CZ) {                                                   \
        const float xxj = fmaf(CX, CX, fmaf(CY, CY, CZ * CZ));                \
        t0 = fmaxf(t0, pdq(CX, CY, CZ, xxj, q0));                             \
        t1 = fmaxf(t1, pdq(CX, CY, CZ, xxj, q1));                             \
        t2 = fmaxf(t2, pdq(CX, CY, CZ, xxj, q2));                             \
        t3 = fmaxf(t3, pdq(CX, CY, CZ, xxj, q3)); }
    #pragma unroll 2
    for (int it = 0; it < 8; ++it) {
        const int j4 = base + it * 256 + l * 4;
        const float4 X = *(const float4*)&xb[j4];
        const float4 Y = *(const float4*)&xb[NP + j4];
        const float4 Z = *(const float4*)&xb[2 * NP + j4];
        CAND1(X.x, Y.x, Z.x) CAND1(X.y, Y.y, Z.y)
        CAND1(X.z, Y.z, Z.z) CAND1(X.w, Y.w, Z.w)
    }
#undef CAND1

    // per-wave sort of 64 lane-maxima; top-32 of each wave into LDS
    t0 = sort64_desc(t0, l);
    t1 = sort64_desc(t1, l);
    t2 = sort64_desc(t2, l);
    t3 = sort64_desc(t3, l);
    if (l < 32) {
        s_mrg[0][w * 32 + l] = t0;
        s_mrg[1][w * 32 + l] = t1;
        s_mrg[2][w * 32 + l] = t2;
        s_mrg[3][w * 32 + l] = t3;
    }
    __syncthreads();

    // each wave merges (full-sorts) 2 queries' merged-64; m32 = sorted[31]
    {
        const int qa = 2 * w, qb = 2 * w + 1;
        const float sa = sort64_desc(s_mrg[qa][l], l);
        const float sb = sort64_desc(s_mrg[qb][l], l);
        if (l == 31) s_thr[qa] = sa - 0x1p-11f;   // margin >= 2*delta
        if (l == 31) s_thr[qb] = sb - 0x1p-11f;
    }
    __syncthreads();

    const float thr0 = s_thr[0];
    const float thr1 = s_thr[1];
    const float thr2 = s_thr[2];
    const float thr3 = s_thr[3];

    // -- pass 2: recompute (L1-hot) and gather survivors (shared arrays) --
#define CAND2(CX, CY, CZ, JOFF) {                                             \
        const float xxj = fmaf(CX, CX, fmaf(CY, CY, CZ * CZ));                \
        const float pA = pdq(CX, CY, CZ, xxj, q0);                            \
        const float pB = pdq(CX, CY, CZ, xxj, q1);                            \
        const float pC = pdq(CX, CY, CZ, xxj, q2);                            \
        const float pD = pdq(CX, CY, CZ, xxj, q3);                            \
        if (pA >= thr0) { const unsigned p = atomicAdd(&s_cnt[0], 1u);        \
                          if (p < 128u) s_sj[0][p] = j4 + (JOFF); }           \
        if (pB >= thr1) { const unsigned p = atomicAdd(&s_cnt[1], 1u);        \
                          if (p < 128u) s_sj[1][p] = j4 + (JOFF); }           \
        if (pC >= thr2) { const unsigned p = atomicAdd(&s_cnt[2], 1u);        \
                          if (p < 128u) s_sj[2][p] = j4 + (JOFF); }           \
        if (pD >= thr3) { const unsigned p = atomicAdd(&s_cnt[3], 1u);        \
                          if (p < 128u) s_sj[3][p] = j4 + (JOFF); } }
    #pragma unroll 2
    for (int it = 0; it < 8; ++it) {
        const int j4 = base + it * 256 + l * 4;
        const float4 X = *(const float4*)&xb[j4];
        const float4 Y = *(const float4*)&xb[NP + j4];
        const float4 Z = *(const float4*)&xb[2 * NP + j4];
        CAND2(X.x, Y.x, Z.x, 0) CAND2(X.y, Y.y, Z.y, 1)
        CAND2(X.z, Y.z, Z.z, 2) CAND2(X.w, Y.w, Z.w, 3)
    }
#undef CAND2
    __syncthreads();

    const float* fb = feats + (size_t)b * NP * NC;

    // -- epilogue: wave 0 -> queries 0,1; wave 1 -> queries 2,3 (wave-local)
#define EPI(QI, QREF) {                                                       \
        const int sc = (int)min(s_cnt[QI], 128u);                             \
        rekey(xb, s_sj[QI], s_sk[QI], sc, l, QREF);                           \
        top32_sel(s_sj[QI], s_sk[QI], sc, l, s_sel[w]);                       \
        pool_row(fb, s_sel[w], l,                                             \
                 pooled + (size_t)((b << 12) | (i0 + QI)) * NC); }
    if (w == 0) { EPI(0, q0) EPI(1, q1) }
    else        { EPI(2, q2) EPI(3, q3) }
#undef EPI
}

// ---------------------------------------------------------------------------
// Kernel B (v4, r23-verbatim): in-place Linear, 512 blocks x 32 rows, full
// Wt staged in LDS (80KB -> 2 blocks/CU). Bit-identical output to v2/v3.
// ---------------------------------------------------------------------------
constexpr int LROWS = 32;
__global__ __launch_bounds__(NT) void linear_v4_kernel(
    float* __restrict__ io,           // [B*N, C] fp32, in-place
    const float* __restrict__ Wt)     // [C, C] transposed: Wt[c][d]
{
    const int t    = threadIdx.x;
    const int row0 = blockIdx.x * LROWS;

    __shared__ float  P[LROWS * NC];  // 16 KiB
    __shared__ float4 sWt[NC * 32];   // 64 KiB: row c = 32 float4

    const float4* src4 = (const float4*)(io + (size_t)row0 * NC);
    #pragma unroll
    for (int m = 0; m < 4; ++m)
        ((float4*)P)[m * NT + t] = src4[m * NT + t];
    const float4* Wt4g = (const float4*)Wt;
    #pragma unroll
    for (int m = 0; m < 16; ++m)
        sWt[m * NT + t] = Wt4g[m * NT + t];       // coalesced 64KB stage
    __syncthreads();

    const int dg = t & 31;            // d = 4*dg .. 4*dg+3
    const int rg = t >> 5;            // rows 4*rg .. 4*rg+3

    float4 a0 = make_float4(0.f,0.f,0.f,0.f);
    float4 a1 = make_float4(0.f,0.f,0.f,0.f);
    float4 a2 = make_float4(0.f,0.f,0.f,0.f);
    float4 a3 = make_float4(0.f,0.f,0.f,0.f);
    const float* Pr = P + rg * 4 * NC;

#define LSTEP(K, PC)                                                          \
    {                                                                         \
        const float4 w = sWt[(c4 * 4 + K) * 32 + dg];                         \
        a0.x = fmaf(p0.PC, w.x, a0.x); a0.y = fmaf(p0.PC, w.y, a0.y);         \
        a0.z = fmaf(p0.PC, w.z, a0.z); a0.w = fmaf(p0.PC, w.w, a0.w);         \
        a1.x = fmaf(p1.PC, w.x, a1.x); a1.y = fmaf(p1.PC, w.y, a1.y);         \
        a1.z = fmaf(p1.PC, w.z, a1.z); a1.w = fmaf(p1.PC, w.w, a1.w);         \
        a2.x = fmaf(p2.PC, w.x, a2.x); a2.y = fmaf(p2.PC, w.y, a2.y);         \
        a2.z = fmaf(p2.PC, w.z, a2.z); a2.w = fmaf(p2.PC, w.w, a2.w);         \
        a3.x = fmaf(p3.PC, w.x, a3.x); a3.y = fmaf(p3.PC, w.y, a3.y);         \
        a3.z = fmaf(p3.PC, w.z, a3.z); a3.w = fmaf(p3.PC, w.w, a3.w);         \
    }

    #pragma unroll 4
    for (int c4 = 0; c4 < NC / 4; ++c4) {
        const float4 p0 = *(const float4*)&Pr[c4 * 4];            // b128 reads
        const float4 p1 = *(const float4*)&Pr[NC + c4 * 4];
        const float4 p2 = *(const float4*)&Pr[2 * NC + c4 * 4];
        const float4 p3 = *(const float4*)&Pr[3 * NC + c4 * 4];
        LSTEP(0, x) LSTEP(1, y) LSTEP(2, z) LSTEP(3, w)
    }
#undef LSTEP

    float4* dst4 = (float4*)(io + (size_t)row0 * NC);
    const int r4 = rg * 4;
    dst4[(r4 + 0) * 32 + dg] = a0;    // all staging reads done pre-barrier
    dst4[(r4 + 1) * 32 + dg] = a1;
    dst4[(r4 + 2) * 32 + dg] = a2;
    dst4[(r4 + 3) * 32 + dg] = a3;
}

// ---------------------------------------------------------------------------
// Fallback (ws-less): old 64-row in-place linear reading W directly.
// ---------------------------------------------------------------------------
__global__ __launch_bounds__(NT) void linear_kernel(
    float* __restrict__ io, const float* __restrict__ W)
{
    const int t = threadIdx.x;
    const int row0 = blockIdx.x * 64;
    __shared__ float P[64 * NC];
    const float* src = io + (size_t)row0 * NC;
    #pragma unroll
    for (int m = 0; m < 8; ++m) {
        const int e4 = m * NT + t;
        *(float4*)&P[e4 * 4] = *(const float4*)&src[e4 * 4];
    }
    __syncthreads();
    const int d = t & (NC - 1);
    const int rbase = (t >> 7) * 32;
    float acc[32];
    #pragma unroll
    for (int k = 0; k < 32; ++k) acc[k] = 0.f;
    const float* Wd = W + (size_t)d * NC;
    for (int c4 = 0; c4 < NC / 4; ++c4) {
        const float4 w = *(const float4*)(Wd + c4 * 4);
        #pragma unroll
        for (int k = 0; k < 32; ++k) {
            const float4 pv = *(const float4*)&P[(rbase + k) * NC + c4 * 4];
            acc[k] = fmaf(pv.x, w.x, acc[k]);
            acc[k] = fmaf(pv.y, w.y, acc[k]);
            acc[k] = fmaf(pv.z, w.z, acc[k]);
            acc[k] = fmaf(pv.w, w.w, acc[k]);
        }
    }
    #pragma unroll
    for (int k = 0; k < 32; ++k)
        io[(size_t)(row0 + rbase + k) * NC + d] = acc[k];
}

// ---------------------------------------------------------------------------
extern "C" void kernel_launch(void* const* d_in, const int* in_sizes, int n_in,
                              void* d_out, int out_size, void* d_ws, size_t ws_size,
                              hipStream_t stream) {
    const float* xyz   = nullptr;  // 49152
    const float* feats = nullptr;  // 2097152
    const float* W     = nullptr;  // 16384
    for (int k = 0; k < n_in; ++k) {
        if      (in_sizes[k] == NB * 3 * NP)       xyz   = (const float*)d_in[k];
        else if (in_sizes[k] == NB * NP * NC)      feats = (const float*)d_in[k];
        else if (in_sizes[k] == NC * NC)           W     = (const float*)d_in[k];
    }
    float* out = (float*)d_out;

    const size_t need = sizeof(float) * (size_t)(NC * NC);
    if (ws_size >= need) {
        float* Wt = (float*)d_ws;                  // 64 KiB
        knn_wave2_kernel<<<NB * NP / NQ, 128, 0, stream>>>(xyz, feats, W, Wt, out);
        linear_v4_kernel<<<NB * NP / LROWS, NT, 0, stream>>>(out, Wt);
    } else {
        knn_wave2_kernel<<<NB * NP / NQ, 128, 0, stream>>>(xyz, feats, W, nullptr, out);
        linear_kernel<<<NB * NP / 64, NT, 0, stream>>>(out, W);
    }
}